// Round 1
// baseline (128.772 us; speedup 1.0000x reference)
//
#include <hip/hip_runtime.h>
#include <hip/hip_bf16.h>

#define MDIM 8192
#define KDIM 512
#define BM 128
#define BN 128
#define BK 32

typedef __attribute__((ext_vector_type(8))) short short8;
typedef __attribute__((ext_vector_type(4))) float f32x4;
typedef __attribute__((ext_vector_type(8))) unsigned short ushort8;

// ---- manual bf16 (RNE) to avoid header API drift; inputs are finite normals ----
__device__ __forceinline__ unsigned short f32_to_bf16_rne(float f) {
    unsigned int u = __float_as_uint(f);
    u += 0x7FFFu + ((u >> 16) & 1u);
    return (unsigned short)(u >> 16);
}
__device__ __forceinline__ float bf16_to_f32(unsigned short s) {
    return __uint_as_float(((unsigned int)s) << 16);
}

__device__ __forceinline__ void gload16(const void* g, void* l) {
    __builtin_amdgcn_global_load_lds(
        (const __attribute__((address_space(1))) void*)g,
        (__attribute__((address_space(3))) void*)l,
        16, 0, 0);
}

// Kernel 1: fp32 -> bf16 copy into ws, plus sq[row] = sum(bf16(x)^2) in fp32.
// One wave per row, 4 rows per block. lane covers 8 contiguous elements.
__global__ __launch_bounds__(256) void rbf_convert(const float* __restrict__ x,
                                                   unsigned short* __restrict__ xb,
                                                   float* __restrict__ sq) {
    const int lane = threadIdx.x & 63;
    const int wave = threadIdx.x >> 6;
    const int row  = blockIdx.x * 4 + wave;

    const float* xr = x + (size_t)row * KDIM + lane * 8;
    float4 v0 = *(const float4*)(xr);
    float4 v1 = *(const float4*)(xr + 4);
    float vals[8] = {v0.x, v0.y, v0.z, v0.w, v1.x, v1.y, v1.z, v1.w};

    ushort8 packed;
    float s = 0.f;
#pragma unroll
    for (int j = 0; j < 8; ++j) {
        unsigned short b = f32_to_bf16_rne(vals[j]);
        packed[j] = b;
        float f = bf16_to_f32(b);
        s += f * f;
    }
    *(ushort8*)(xb + (size_t)row * KDIM + lane * 8) = packed;

#pragma unroll
    for (int off = 32; off > 0; off >>= 1) s += __shfl_xor(s, off, 64);
    if (lane == 0) sq[row] = s;
}

// Kernel 2: 128x128 tile NT-GEMM (gram = Xb * Xb^T) with fused RBF epilogue.
// 4 waves (2x2), each wave owns a 64x64 sub-tile = 4x4 fragments of 16x16.
__global__ __launch_bounds__(256) void rbf_gemm(const unsigned short* __restrict__ xb,
                                                const float* __restrict__ sq,
                                                float* __restrict__ out) {
    __shared__ unsigned short As[BM * BK];  // [row][k], row stride 32 elem = 64 B
    __shared__ unsigned short Bs[BN * BK];

    const int t    = threadIdx.x;
    const int lane = t & 63;
    const int wave = t >> 6;
    const int wr   = wave >> 1;          // 0..1
    const int wc   = wave & 1;           // 0..1
    const int brow = blockIdx.y * BM;
    const int bcol = blockIdx.x * BN;

    f32x4 acc[4][4] = {};

    // staging: 256 threads x 16B = 4 KB/issue; tile = 8 KB -> 2 issues per operand
    const int srow  = t >> 2;            // 0..63
    const int selem = (t & 3) * 8;       // bf16 element offset within a 32-elem row
    const int lds0  = wave * 512;        // element offset of wave-uniform LDS base
    const int lds1  = 2048 + wave * 512;

    // fragment read offsets (A: m = lane%16, k = (lane/16)*8 + j ; B symmetric)
    const int fr = lane & 15;
    const int fk = (lane >> 4) * 8;

    for (int kk = 0; kk < KDIM; kk += BK) {
        const unsigned short* gA0 = xb + (size_t)(brow + srow)      * KDIM + kk + selem;
        const unsigned short* gA1 = xb + (size_t)(brow + 64 + srow) * KDIM + kk + selem;
        const unsigned short* gB0 = xb + (size_t)(bcol + srow)      * KDIM + kk + selem;
        const unsigned short* gB1 = xb + (size_t)(bcol + 64 + srow) * KDIM + kk + selem;
        gload16(gA0, &As[lds0]);
        gload16(gA1, &As[lds1]);
        gload16(gB0, &Bs[lds0]);
        gload16(gB1, &Bs[lds1]);
        __syncthreads();   // compiler emits s_waitcnt vmcnt(0) before s_barrier

        short8 a[4], b[4];
#pragma unroll
        for (int m = 0; m < 4; ++m)
            a[m] = *(const short8*)&As[(wr * 64 + m * 16 + fr) * BK + fk];
#pragma unroll
        for (int n = 0; n < 4; ++n)
            b[n] = *(const short8*)&Bs[(wc * 64 + n * 16 + fr) * BK + fk];

#pragma unroll
        for (int m = 0; m < 4; ++m)
#pragma unroll
            for (int n = 0; n < 4; ++n)
                acc[m][n] = __builtin_amdgcn_mfma_f32_16x16x32_bf16(a[m], b[n], acc[m][n], 0, 0, 0);

        __syncthreads();
    }

    // epilogue: C/D layout col = lane&15, row = (lane>>4)*4 + j  [m89-verified]
    const int cg = lane >> 4;
    const int cl = lane & 15;
#pragma unroll
    for (int n = 0; n < 4; ++n) {
        const int col = bcol + wc * 64 + n * 16 + cl;
        const float sqc = sq[col];
#pragma unroll
        for (int m = 0; m < 4; ++m) {
#pragma unroll
            for (int j = 0; j < 4; ++j) {
                const int row = brow + wr * 64 + m * 16 + cg * 4 + j;
                float d2 = sq[row] + sqc - 2.0f * acc[m][n][j];
                d2 = fmaxf(d2, 0.0f);
                out[(size_t)row * MDIM + col] = __expf(-0.5f * d2);
            }
        }
    }
}

extern "C" void kernel_launch(void* const* d_in, const int* in_sizes, int n_in,
                              void* d_out, int out_size, void* d_ws, size_t ws_size,
                              hipStream_t stream) {
    const float* x = (const float*)d_in[0];
    float* out = (float*)d_out;

    // ws layout: [ sq: 8192 f32 = 32 KB ][ xb: 8192*512 bf16 = 8 MB ]
    float* sq = (float*)d_ws;
    unsigned short* xb = (unsigned short*)((char*)d_ws + MDIM * sizeof(float));

    rbf_convert<<<MDIM / 4, 256, 0, stream>>>(x, xb, sq);
    rbf_gemm<<<dim3(MDIM / BN, MDIM / BM), 256, 0, stream>>>(xb, sq, out);
}

// Round 2
// 122.213 us; speedup vs baseline: 1.0537x; 1.0537x over previous
//
#include <hip/hip_runtime.h>
#include <hip/hip_bf16.h>

#define MDIM 8192
#define KDIM 512
#define NT   8   // K-tiles of 64

typedef __attribute__((ext_vector_type(8))) short short8;
typedef __attribute__((ext_vector_type(4))) float f32x4;
typedef __attribute__((ext_vector_type(8))) unsigned short ushort8;

__device__ __forceinline__ unsigned short f32_to_bf16_rne(float f) {
    unsigned int u = __float_as_uint(f);
    u += 0x7FFFu + ((u >> 16) & 1u);
    return (unsigned short)(u >> 16);
}
__device__ __forceinline__ float bf16_to_f32(unsigned short s) {
    return __uint_as_float(((unsigned int)s) << 16);
}

__device__ __forceinline__ void gload16(const void* g, void* l) {
    __builtin_amdgcn_global_load_lds(
        (const __attribute__((address_space(1))) void*)g,
        (__attribute__((address_space(3))) void*)l,
        16, 0, 0);
}

// Kernel 1: fp32 -> bf16 into ws + sq[row] = sum(bf16(x)^2) (fp32).
__global__ __launch_bounds__(256) void rbf_convert(const float* __restrict__ x,
                                                   unsigned short* __restrict__ xb,
                                                   float* __restrict__ sq) {
    const int lane = threadIdx.x & 63;
    const int wave = threadIdx.x >> 6;
    const int row  = blockIdx.x * 4 + wave;

    const float* xr = x + (size_t)row * KDIM + lane * 8;
    float4 v0 = *(const float4*)(xr);
    float4 v1 = *(const float4*)(xr + 4);
    float vals[8] = {v0.x, v0.y, v0.z, v0.w, v1.x, v1.y, v1.z, v1.w};

    ushort8 packed;
    float s = 0.f;
#pragma unroll
    for (int j = 0; j < 8; ++j) {
        unsigned short b = f32_to_bf16_rne(vals[j]);
        packed[j] = b;
        float f = bf16_to_f32(b);
        s += f * f;
    }
    *(ushort8*)(xb + (size_t)row * KDIM + lane * 8) = packed;

#pragma unroll
    for (int off = 32; off > 0; off >>= 1) s += __shfl_xor(s, off, 64);
    if (lane == 0) sq[row] = s;
}

// ------------------- 256x256 8-phase pipelined NT-GEMM + RBF epilogue -----
// 8 waves (2M x 4N), per-wave 128x64 output = 8x4 frags of 16x16, BK=64.
// LDS: 2 buffers x (A 32KB + B 32KB) = 128 KiB, XOR-swizzled (T2, both-sides).
extern __shared__ char lds[];

#define BAR()  __builtin_amdgcn_s_barrier()
#define LGK()  do { asm volatile("s_waitcnt lgkmcnt(0)" ::: "memory"); \
                    __builtin_amdgcn_sched_barrier(0); } while (0)
#define VMW(N) asm volatile("s_waitcnt vmcnt(" #N ")" ::: "memory")

#define READ_A(BUF, MQ) do {                                                   \
    _Pragma("unroll")                                                          \
    for (int m = 0; m < 4; ++m) {                                              \
        const char* p_ = &lds[(BUF) * 65536 +                                  \
                              (wr * 128 + (MQ) * 64 + m * 16 + fr) * 128];     \
        af[m][0] = *(const short8*)(p_ + c0);                                  \
        af[m][1] = *(const short8*)(p_ + c1);                                  \
    } } while (0)

#define READ_B(BUF, NQ) do {                                                   \
    _Pragma("unroll")                                                          \
    for (int nn = 0; nn < 2; ++nn) {                                           \
        const char* p_ = &lds[(BUF) * 65536 + 32768 +                          \
                              (wc * 64 + (NQ) * 32 + nn * 16 + fr) * 128];     \
        bf4[(NQ) * 2 + nn][0] = *(const short8*)(p_ + c0);                     \
        bf4[(NQ) * 2 + nn][1] = *(const short8*)(p_ + c1);                     \
    } } while (0)

#define MFMA_Q(MQ, NQ) do {                                                    \
    __builtin_amdgcn_s_setprio(1);                                             \
    _Pragma("unroll")                                                          \
    for (int m = 0; m < 4; ++m) {                                              \
        _Pragma("unroll")                                                      \
        for (int nn = 0; nn < 2; ++nn) {                                       \
            f32x4 a_ = acc[(MQ) * 4 + m][(NQ) * 2 + nn];                       \
            a_ = __builtin_amdgcn_mfma_f32_16x16x32_bf16(af[m][0], bf4[(NQ)*2+nn][0], a_, 0, 0, 0); \
            a_ = __builtin_amdgcn_mfma_f32_16x16x32_bf16(af[m][1], bf4[(NQ)*2+nn][1], a_, 0, 0, 0); \
            acc[(MQ) * 4 + m][(NQ) * 2 + nn] = a_;                             \
        } }                                                                    \
    __builtin_amdgcn_s_setprio(0); } while (0)

__global__ __launch_bounds__(512, 2) void rbf_gemm(const unsigned short* __restrict__ xb,
                                                   const float* __restrict__ sq,
                                                   float* __restrict__ out) {
    const int t    = threadIdx.x;
    const int lane = t & 63;
    const int wave = t >> 6;
    const int wr   = wave >> 2;   // 0..1
    const int wc   = wave & 3;    // 0..3

    // T1: XCD-aware swizzle (nwg=1024, 1024%8==0 -> simple bijective form)
    const int bid  = blockIdx.x;
    const int swz  = (bid & 7) * 128 + (bid >> 3);
    const int brow = (swz >> 5) * 256;
    const int bcol = (swz & 31) * 256;

    // staging coords: issue covers 64 rows x 128B; thread t -> row t>>3, slot t&7.
    // T2 both-sides: LDS dest linear, global source slot pre-XORed (involution).
    const int srow    = t >> 3;
    const int sslot16 = ((t & 7) ^ (srow & 7)) * 16;

    // fragment read coords (reader applies the same XOR)
    const int fr = lane & 15;
    const int fo = lane >> 4;
    const int rx = (fr & 7) << 4;
    const int c0 = (fo * 16) ^ rx;
    const int c1 = (64 + fo * 16) ^ rx;

    f32x4 acc[8][4] = {};
    short8 af[4][2], bf4[4][2];

    const char* gxb = (const char*)xb;

    // stage pair s (0..3) of K-tile kt into buffer buf: s0=A q01, s1=A q23, s2=B q01, s3=B q23
    auto stage2 = [&](int kt, int buf, int s) {
        const int op      = s >> 1;
        const int q0      = (s & 1) * 2;
        const int rowbase = op ? bcol : brow;
        const size_t koff = (size_t)kt * 128 + sslot16;
        const char* g0 = gxb + (size_t)(rowbase + q0 * 64 + srow) * 1024 + koff;
        const char* g1 = gxb + (size_t)(rowbase + q0 * 64 + 64 + srow) * 1024 + koff;
        char* l0 = &lds[buf * 65536 + op * 32768 + q0 * 8192 + wave * 1024];
        gload16(g0, l0);
        gload16(g1, l0 + 8192);
    };

    // prologue: fully stage tiles 0 (buf0) and 1 (buf1) = 16 loads/wave
    stage2(0, 0, 0); stage2(0, 0, 1); stage2(0, 0, 2); stage2(0, 0, 3);
    stage2(1, 1, 0); stage2(1, 1, 1); stage2(1, 1, 2); stage2(1, 1, 3);
    VMW(8);   // tile0 landed (tile1's 8 still allowed in flight)
    BAR();

#pragma unroll 1
    for (int i = 0; i < NT / 2; ++i) {
        const bool sO  = (i > 0);            // continue staging odd tile 2i+1 (issues 1..3)
        const bool sE  = (i < NT / 2 - 1);   // stage tiles 2i+2 / first pair of 2i+3
        const int ktO  = 2 * i + 1;
        const int ktE2 = 2 * i + 2;
        const int ktO2 = 2 * i + 3;

        // p0
        READ_A(0, 0); READ_B(0, 0);
        if (sO) stage2(ktO, 1, 1);
        BAR(); LGK(); MFMA_Q(0, 0); BAR();
        // p1
        READ_B(0, 1);
        if (sO) stage2(ktO, 1, 2);
        BAR(); LGK(); MFMA_Q(0, 1); BAR();
        // p2
        READ_A(0, 1);
        if (sO) stage2(ktO, 1, 3);
        BAR(); LGK(); MFMA_Q(1, 0); BAR();
        // p3  (counted wait: odd tile ready; 2 younger loads stay in flight)
        if (sE) stage2(ktE2, 0, 0);
        BAR(); LGK(); MFMA_Q(1, 1);
        if (sE) { VMW(2); } else { VMW(0); }
        BAR();
        // p4
        READ_A(1, 0); READ_B(1, 0);
        if (sE) stage2(ktE2, 0, 1);
        BAR(); LGK(); MFMA_Q(0, 0); BAR();
        // p5
        READ_B(1, 1);
        if (sE) stage2(ktE2, 0, 2);
        BAR(); LGK(); MFMA_Q(0, 1); BAR();
        // p6
        READ_A(1, 1);
        if (sE) stage2(ktE2, 0, 3);
        BAR(); LGK(); MFMA_Q(1, 0); BAR();
        // p7  (counted wait: next even tile ready)
        if (sE) stage2(ktO2, 1, 0);
        BAR(); LGK(); MFMA_Q(1, 1);
        if (sE) { VMW(2); } else { VMW(0); }
        BAR();
    }

    // epilogue: C/D layout col = lane&15, row = (lane>>4)*4 + j
    const int cg = lane >> 4;
    const int cl = lane & 15;
#pragma unroll
    for (int n = 0; n < 4; ++n) {
        const int col   = bcol + wc * 64 + n * 16 + cl;
        const float sqc = sq[col];
#pragma unroll
        for (int m = 0; m < 8; ++m) {
#pragma unroll
            for (int j = 0; j < 4; ++j) {
                const int row = brow + wr * 128 + m * 16 + cg * 4 + j;
                float d2 = sq[row] + sqc - 2.0f * acc[m][n][j];
                d2 = fmaxf(d2, 0.0f);
                out[(size_t)row * MDIM + col] = __expf(-0.5f * d2);
            }
        }
    }
}

extern "C" void kernel_launch(void* const* d_in, const int* in_sizes, int n_in,
                              void* d_out, int out_size, void* d_ws, size_t ws_size,
                              hipStream_t stream) {
    const float* x = (const float*)d_in[0];
    float* out = (float*)d_out;

    float* sq = (float*)d_ws;
    unsigned short* xb = (unsigned short*)((char*)d_ws + MDIM * sizeof(float));

    // allow 128 KiB dynamic LDS (no-op if already permitted; host-side, capture-safe)
    static int lds_ok = 0;
    if (!lds_ok) {
        hipFuncSetAttribute((const void*)rbf_gemm,
                            hipFuncAttributeMaxDynamicSharedMemorySize, 131072);
        lds_ok = 1;
    }

    rbf_convert<<<MDIM / 4, 256, 0, stream>>>(x, xb, sq);
    rbf_gemm<<<dim3(1024), 512, 131072, stream>>>(xb, sq, out);
}